// Round 2
// baseline (361.673 us; speedup 1.0000x reference)
//
#include <hip/hip_runtime.h>
#include <hip/hip_bf16.h>

#define Bb 8
#define Cch 256
#define Nn 2048
#define Mm 2048
#define KKEEP 1638
#define RANK 410   /* Nn - KKEEP, 0-indexed ascending rank of threshold */

typedef __hip_bfloat16 bf16;
typedef __attribute__((ext_vector_type(8))) short bf16x8;
typedef __attribute__((ext_vector_type(4))) float f32x4;
typedef unsigned int u32;
typedef unsigned short u16;

__device__ __forceinline__ void gload_lds16(const void* g, void* l) {
  __builtin_amdgcn_global_load_lds((const __attribute__((address_space(1))) u32*)g,
                                   (__attribute__((address_space(3))) u32*)l, 16, 0, 0);
}

// ---------------- norms: inv[b*NN+n] = 1/max(||x[b,:,n]||, 1e-12) ----------
__global__ __launch_bounds__(256) void norm_kernel(const float* __restrict__ t,
                                                   float* __restrict__ inv) {
  int idx = blockIdx.x * 256 + threadIdx.x;          // b*Nn + n
  int b = idx >> 11, n = idx & (Nn - 1);
  const float* p = t + (size_t)b * Cch * Nn + n;
  float s = 0.f;
  #pragma unroll 4
  for (int c = 0; c < Cch; ++c) { float v = p[(size_t)c * Nn]; s += v * v; }
  inv[idx] = 1.f / fmaxf(sqrtf(s), 1e-12f);
}

// ------------- transpose+scale+bf16: out[b][n][c] = bf16(in[b][c][n]*inv[b][n])
__global__ __launch_bounds__(256) void transpose_scale(const float* __restrict__ in,
                                                       const float* __restrict__ inv,
                                                       bf16* __restrict__ outp) {
  __shared__ float tile[32][33];
  int b = blockIdx.z;
  int n0 = blockIdx.x * 32, c0 = blockIdx.y * 32;
  int tx = threadIdx.x, ty = threadIdx.y;
  const float* src = in + (size_t)b * Cch * Nn;
  #pragma unroll
  for (int i = 0; i < 32; i += 8)
    tile[ty + i][tx] = src[(size_t)(c0 + ty + i) * Nn + n0 + tx];
  __syncthreads();
  bf16* dst = outp + (size_t)b * Nn * Cch;
  #pragma unroll
  for (int i = 0; i < 32; i += 8) {
    int n = n0 + ty + i;
    float sc = inv[(b << 11) + n];
    dst[(size_t)n * Cch + c0 + tx] = __float2bfloat16(tile[tx][ty + i] * sc);
  }
}

// ------------- straight f32 -> bf16 convert -------------------------------
__global__ __launch_bounds__(256) void cvt_bf16(const float* __restrict__ in,
                                                bf16* __restrict__ outp, size_t n4) {
  size_t i = (size_t)blockIdx.x * 256 + threadIdx.x;
  size_t stride = (size_t)gridDim.x * 256;
  for (; i < n4; i += stride) {
    float4 v = ((const float4*)in)[i];
    union { bf16 h[4]; uint2 u; } pk;
    pk.h[0] = __float2bfloat16(v.x); pk.h[1] = __float2bfloat16(v.y);
    pk.h[2] = __float2bfloat16(v.z); pk.h[3] = __float2bfloat16(v.w);
    *(uint2*)&outp[i * 4] = pk.u;
  }
}

// ------------- m97-style 128x128 bf16 MFMA GEMM, C = A * Bt^T -------------
// A: [batch][Mrows][K] bf16 (K contiguous), Bt: [batch][Ncols][K] bf16
template <int STORE_BF16, int LEAKY>
__global__ __launch_bounds__(256) void gemm_bt(const bf16* __restrict__ A,
                                               const bf16* __restrict__ Bt,
                                               void* __restrict__ Cout,
                                               int Mrows, int Ncols, int K) {
  __shared__ bf16 aT[128 * 32];
  __shared__ bf16 bT[128 * 32];
  const int b = blockIdx.z;
  const int m0 = blockIdx.x * 128;
  const int n0 = blockIdx.y * 128;
  const bf16* Ab = A + (size_t)b * Mrows * K;
  const bf16* Bbp = Bt + (size_t)b * Ncols * K;
  const int tid = threadIdx.x;
  const int lane = tid & 63;
  const int wave = tid >> 6;
  const int wr = wave >> 1, wc = wave & 1;

  f32x4 acc[4][4];
  #pragma unroll
  for (int i = 0; i < 4; i++)
    #pragma unroll
    for (int j = 0; j < 4; j++) acc[i][j] = (f32x4){0.f, 0.f, 0.f, 0.f};

  const int srow = tid >> 2;
  const int scol = (tid & 3) * 8;
  const bf16* gA0 = Ab + (size_t)(m0 + srow) * K + scol;
  const bf16* gB0 = Bbp + (size_t)(n0 + srow) * K + scol;
  bf16* lA = aT + wave * 512;   // wave-uniform LDS base (lane*16B auto-added)
  bf16* lB = bT + wave * 512;

  const int fm = lane & 15;
  const int kb = (lane >> 4) * 8;

  for (int kt = 0; kt < K; kt += 32) {
    gload_lds16(gA0 + kt, lA);
    gload_lds16(gA0 + (size_t)64 * K + kt, lA + 2048);
    gload_lds16(gB0 + kt, lB);
    gload_lds16(gB0 + (size_t)64 * K + kt, lB + 2048);
    __syncthreads();
    bf16x8 af[4], bf_[4];
    #pragma unroll
    for (int mf = 0; mf < 4; mf++)
      af[mf] = *(const bf16x8*)&aT[(wr * 64 + mf * 16 + fm) * 32 + kb];
    #pragma unroll
    for (int nf = 0; nf < 4; nf++)
      bf_[nf] = *(const bf16x8*)&bT[(wc * 64 + nf * 16 + fm) * 32 + kb];
    #pragma unroll
    for (int mf = 0; mf < 4; mf++)
      #pragma unroll
      for (int nf = 0; nf < 4; nf++)
        acc[mf][nf] = __builtin_amdgcn_mfma_f32_16x16x32_bf16(af[mf], bf_[nf], acc[mf][nf], 0, 0, 0);
    __syncthreads();
  }

  const int orow = (lane >> 4) * 4;
  const int ocol = lane & 15;
  if (STORE_BF16) {
    bf16* Cb = (bf16*)Cout + (size_t)b * Mrows * Ncols;
    #pragma unroll
    for (int mf = 0; mf < 4; mf++)
      #pragma unroll
      for (int nf = 0; nf < 4; nf++)
        #pragma unroll
        for (int r = 0; r < 4; r++) {
          int gm = m0 + wr * 64 + mf * 16 + orow + r;
          int gn = n0 + wc * 64 + nf * 16 + ocol;
          Cb[(size_t)gm * Ncols + gn] = __float2bfloat16(acc[mf][nf][r]);
        }
  } else {
    float* Cf = (float*)Cout + (size_t)b * Mrows * Ncols;
    #pragma unroll
    for (int mf = 0; mf < 4; mf++)
      #pragma unroll
      for (int nf = 0; nf < 4; nf++)
        #pragma unroll
        for (int r = 0; r < 4; r++) {
          int gm = m0 + wr * 64 + mf * 16 + orow + r;
          int gn = n0 + wc * 64 + nf * 16 + ocol;
          float v = acc[mf][nf][r];
          if (LEAKY) v = v >= 0.f ? v : 0.01f * v;
          Cf[(size_t)gm * Ncols + gn] = v;
        }
  }
}

// ------------- per-row softmax + exact top-k mask (in place, bf16) --------
__global__ __launch_bounds__(256) void row_topk_softmax(bf16* __restrict__ S) {
  int tid = threadIdx.x;
  bf16* row = S + (size_t)blockIdx.x * Nn;
  uint4 raw = ((const uint4*)row)[tid];
  u32 w[4] = {raw.x, raw.y, raw.z, raw.w};
  u16 u[8]; float f[8]; u16 key[8];
  #pragma unroll
  for (int j = 0; j < 4; j++) { u[2 * j] = (u16)(w[j] & 0xFFFF); u[2 * j + 1] = (u16)(w[j] >> 16); }
  #pragma unroll
  for (int j = 0; j < 8; j++) {
    u32 bits = ((u32)u[j]) << 16;
    __builtin_memcpy(&f[j], &bits, 4);
    key[j] = (u[j] & 0x8000) ? (u16)(~u[j]) : (u16)(u[j] | 0x8000);
  }
  __shared__ float red[256];
  float mx = f[0];
  #pragma unroll
  for (int j = 1; j < 8; j++) mx = fmaxf(mx, f[j]);
  red[tid] = mx; __syncthreads();
  for (int s = 128; s > 0; s >>= 1) { if (tid < s) red[tid] = fmaxf(red[tid], red[tid + s]); __syncthreads(); }
  mx = red[0]; __syncthreads();
  float e[8]; float se = 0.f;
  #pragma unroll
  for (int j = 0; j < 8; j++) { e[j] = __expf(f[j] - mx); se += e[j]; }
  red[tid] = se; __syncthreads();
  for (int s = 128; s > 0; s >>= 1) { if (tid < s) red[tid] += red[tid + s]; __syncthreads(); }
  float inv_denom = 1.f / red[0]; __syncthreads();

  __shared__ u32 hist[256];
  __shared__ u32 sres[2];
  hist[tid] = 0; __syncthreads();
  #pragma unroll
  for (int j = 0; j < 8; j++) atomicAdd(&hist[key[j] >> 8], 1u);
  __syncthreads();
  if (tid == 0) {
    u32 cum = 0;
    for (int i = 0; i < 256; i++) { u32 c = hist[i]; if (cum + c > (u32)RANK) { sres[0] = i; sres[1] = cum; break; } cum += c; }
  }
  __syncthreads();
  u32 b1 = sres[0], below = sres[1];
  hist[tid] = 0; __syncthreads();
  #pragma unroll
  for (int j = 0; j < 8; j++) if ((u32)(key[j] >> 8) == b1) atomicAdd(&hist[key[j] & 0xFF], 1u);
  __syncthreads();
  if (tid == 0) {
    u32 cum = below;
    for (int i = 0; i < 256; i++) { cum += hist[i]; if (cum > (u32)RANK) { sres[0] = (b1 << 8) | (u32)i; sres[1] = cum; break; } }
  }
  __syncthreads();
  u16 tkey = (u16)sres[0];
  int keepEq = KKEEP - (Nn - (int)sres[1]);
  int eqc = 0;
  #pragma unroll
  for (int j = 0; j < 8; j++) eqc += (key[j] == tkey);
  hist[tid] = (u32)eqc; __syncthreads();
  if (tid == 0) { u32 run = 0; for (int i = 0; i < 256; i++) { u32 t = hist[i]; hist[i] = run; run += t; } }
  __syncthreads();
  int eqseen = (int)hist[tid];

  u16 ob[8];
  #pragma unroll
  for (int j = 0; j < 8; j++) {
    float p = 0.f;
    if (key[j] > tkey) p = e[j] * inv_denom;
    else if (key[j] == tkey) { if (eqseen < keepEq) p = e[j] * inv_denom; eqseen++; }
    u32 pb; __builtin_memcpy(&pb, &p, 4);
    pb += 0x7FFF + ((pb >> 16) & 1);
    ob[j] = (u16)(pb >> 16);
  }
  uint4 outv;
  outv.x = (u32)ob[0] | ((u32)ob[1] << 16);
  outv.y = (u32)ob[2] | ((u32)ob[3] << 16);
  outv.z = (u32)ob[4] | ((u32)ob[5] << 16);
  outv.w = (u32)ob[6] | ((u32)ob[7] << 16);
  ((uint4*)row)[tid] = outv;
}

// ------------- BN stats ----------------------------------------------------
__global__ __launch_bounds__(256) void bn_partial(const float* __restrict__ y,
                                                  float* __restrict__ partial) {
  int bc = blockIdx.x;
  const float* p = y + (size_t)bc * Mm;
  int tid = threadIdx.x;
  float s = 0.f, ss = 0.f;
  for (int i = tid; i < Mm; i += 256) { float v = p[i]; s += v; ss += v * v; }
  __shared__ float r1[256], r2[256];
  r1[tid] = s; r2[tid] = ss; __syncthreads();
  for (int k = 128; k > 0; k >>= 1) { if (tid < k) { r1[tid] += r1[tid + k]; r2[tid] += r2[tid + k]; } __syncthreads(); }
  if (tid == 0) { partial[bc * 2] = r1[0]; partial[bc * 2 + 1] = r2[0]; }
}

__global__ __launch_bounds__(256) void bn_finalize(const float* __restrict__ partial,
                                                   const float* __restrict__ bnw,
                                                   const float* __restrict__ bnb,
                                                   float* __restrict__ scsh) {
  int c = threadIdx.x;
  float s = 0.f, ss = 0.f;
  for (int b = 0; b < Bb; b++) { s += partial[(b * Cch + c) * 2]; ss += partial[(b * Cch + c) * 2 + 1]; }
  float cnt = (float)(Bb * Mm);
  float mean = s / cnt;
  float var = ss / cnt - mean * mean;
  float scale = bnw[c] / sqrtf(var + 1e-5f);
  scsh[c * 2] = scale;
  scsh[c * 2 + 1] = bnb[c] - mean * scale;
}

// ------------- final: out = (y*scale+shift)*gamma + tg --------------------
__global__ __launch_bounds__(256) void final_kernel(float* io, const float* __restrict__ tg,
                                                    const float* __restrict__ scsh,
                                                    const float* __restrict__ gamma) {
  size_t n4 = (size_t)Bb * Cch * Mm / 4;
  float g = gamma[0];
  size_t stride = (size_t)gridDim.x * 256;
  for (size_t i = (size_t)blockIdx.x * 256 + threadIdx.x; i < n4; i += stride) {
    int c = (int)((i * 4 / Mm) % Cch);
    float4 v = ((const float4*)io)[i];
    float4 t = ((const float4*)tg)[i];
    float sc = scsh[c * 2], sh = scsh[c * 2 + 1];
    v.x = (v.x * sc + sh) * g + t.x;
    v.y = (v.y * sc + sh) * g + t.y;
    v.z = (v.z * sc + sh) * g + t.z;
    v.w = (v.w * sc + sh) * g + t.w;
    ((float4*)io)[i] = v;
  }
}

extern "C" void kernel_launch(void* const* d_in, const int* in_sizes, int n_in,
                              void* d_out, int out_size, void* d_ws, size_t ws_size,
                              hipStream_t stream) {
  (void)in_sizes; (void)n_in; (void)out_size; (void)ws_size;
  const float* x   = (const float*)d_in[0];
  const float* tg  = (const float*)d_in[1];
  const float* gamma = (const float*)d_in[2];
  const float* bnw = (const float*)d_in[3];
  const float* bnb = (const float*)d_in[4];
  float* out = (float*)d_out;

  char* ws = (char*)d_ws;
  float* inv_nx = (float*)ws; ws += (size_t)Bb * Nn * 4;
  float* inv_nt = (float*)ws; ws += (size_t)Bb * Mm * 4;
  bf16* xnT  = (bf16*)ws; ws += (size_t)Bb * Nn * Cch * 2;
  bf16* tgnT = (bf16*)ws; ws += (size_t)Bb * Mm * Cch * 2;
  bf16* xb   = (bf16*)ws; ws += (size_t)Bb * Cch * Nn * 2;
  bf16* S    = (bf16*)ws; ws += (size_t)Bb * Mm * Nn * 2;
  float* partial = (float*)ws; ws += (size_t)Bb * Cch * 2 * 4;
  float* scsh = (float*)ws; ws += (size_t)Cch * 2 * 4;

  norm_kernel<<<Bb * Nn / 256, 256, 0, stream>>>(x, inv_nx);
  norm_kernel<<<Bb * Mm / 256, 256, 0, stream>>>(tg, inv_nt);
  transpose_scale<<<dim3(Nn / 32, Cch / 32, Bb), dim3(32, 8), 0, stream>>>(x, inv_nx, xnT);
  transpose_scale<<<dim3(Mm / 32, Cch / 32, Bb), dim3(32, 8), 0, stream>>>(tg, inv_nt, tgnT);
  cvt_bf16<<<2048, 256, 0, stream>>>(x, xb, (size_t)Bb * Cch * Nn / 4);
  // S[b][m][n] = sum_c tgnT[b][m][c] * xnT[b][n][c]
  gemm_bt<1, 0><<<dim3(Mm / 128, Nn / 128, Bb), 256, 0, stream>>>(tgnT, xnT, S, Mm, Nn, Cch);
  row_topk_softmax<<<Bb * Mm, 256, 0, stream>>>(S);
  // out[b][c][m] = leaky( sum_n xb[b][c][n] * adj[b][m][n] )
  gemm_bt<0, 1><<<dim3(Cch / 128, Mm / 128, Bb), 256, 0, stream>>>(xb, S, out, Cch, Mm, Nn);
  bn_partial<<<Bb * Cch, 256, 0, stream>>>(out, partial);
  bn_finalize<<<1, 256, 0, stream>>>(partial, bnw, bnb, scsh);
  final_kernel<<<2048, 256, 0, stream>>>(out, tg, scsh, gamma);
}

// Round 3
// 236.548 us; speedup vs baseline: 1.5290x; 1.5290x over previous
//
#include <hip/hip_runtime.h>
#include <hip/hip_bf16.h>

#define Bb 8
#define Cch 256
#define Nn 2048
#define Mm 2048
#define KKEEP 1638
#define RANK 410   /* Nn - KKEEP, 0-indexed ascending rank of threshold */

typedef __hip_bfloat16 bf16;
typedef __attribute__((ext_vector_type(8))) short bf16x8;
typedef __attribute__((ext_vector_type(4))) float f32x4;
typedef unsigned int u32;
typedef unsigned short u16;

__device__ __forceinline__ void gload_lds16(const void* g, void* l) {
  __builtin_amdgcn_global_load_lds((const __attribute__((address_space(1))) u32*)g,
                                   (__attribute__((address_space(3))) u32*)l, 16, 0, 0);
}

// ---------------- norms: inv[b*NN+n] = 1/max(||x[b,:,n]||, 1e-12) ----------
__global__ __launch_bounds__(256) void norm_kernel(const float* __restrict__ t,
                                                   float* __restrict__ inv) {
  int idx = blockIdx.x * 256 + threadIdx.x;          // b*Nn + n
  int b = idx >> 11, n = idx & (Nn - 1);
  const float* p = t + (size_t)b * Cch * Nn + n;
  float s = 0.f;
  #pragma unroll 4
  for (int c = 0; c < Cch; ++c) { float v = p[(size_t)c * Nn]; s += v * v; }
  inv[idx] = 1.f / fmaxf(sqrtf(s), 1e-12f);
}

// ------------- transpose+scale+bf16: out[b][n][c] = bf16(in[b][c][n]*inv[b][n])
__global__ __launch_bounds__(256) void transpose_scale(const float* __restrict__ in,
                                                       const float* __restrict__ inv,
                                                       bf16* __restrict__ outp) {
  __shared__ float tile[32][33];
  int b = blockIdx.z;
  int n0 = blockIdx.x * 32, c0 = blockIdx.y * 32;
  int tx = threadIdx.x, ty = threadIdx.y;
  const float* src = in + (size_t)b * Cch * Nn;
  #pragma unroll
  for (int i = 0; i < 32; i += 8)
    tile[ty + i][tx] = src[(size_t)(c0 + ty + i) * Nn + n0 + tx];
  __syncthreads();
  bf16* dst = outp + (size_t)b * Nn * Cch;
  #pragma unroll
  for (int i = 0; i < 32; i += 8) {
    int n = n0 + ty + i;
    float sc = inv[(b << 11) + n];
    dst[(size_t)n * Cch + c0 + tx] = __float2bfloat16(tile[tx][ty + i] * sc);
  }
}

// ------------- straight f32 -> bf16 convert -------------------------------
__global__ __launch_bounds__(256) void cvt_bf16(const float* __restrict__ in,
                                                bf16* __restrict__ outp, size_t n4) {
  size_t i = (size_t)blockIdx.x * 256 + threadIdx.x;
  size_t stride = (size_t)gridDim.x * 256;
  for (; i < n4; i += stride) {
    float4 v = ((const float4*)in)[i];
    union { bf16 h[4]; uint2 u; } pk;
    pk.h[0] = __float2bfloat16(v.x); pk.h[1] = __float2bfloat16(v.y);
    pk.h[2] = __float2bfloat16(v.z); pk.h[3] = __float2bfloat16(v.w);
    *(uint2*)&outp[i * 4] = pk.u;
  }
}

// ------------- m97-style 128x128 bf16 MFMA GEMM, C = A * Bt^T -------------
// A: [batch][Mrows][K] bf16 (K contiguous), Bt: [batch][Ncols][K] bf16
template <int STORE_BF16, int LEAKY>
__global__ __launch_bounds__(256) void gemm_bt(const bf16* __restrict__ A,
                                               const bf16* __restrict__ Bt,
                                               void* __restrict__ Cout,
                                               int Mrows, int Ncols, int K) {
  __shared__ bf16 aT[128 * 32];
  __shared__ bf16 bT[128 * 32];
  const int b = blockIdx.z;
  const int m0 = blockIdx.x * 128;
  const int n0 = blockIdx.y * 128;
  const bf16* Ab = A + (size_t)b * Mrows * K;
  const bf16* Bbp = Bt + (size_t)b * Ncols * K;
  const int tid = threadIdx.x;
  const int lane = tid & 63;
  const int wave = tid >> 6;
  const int wr = wave >> 1, wc = wave & 1;

  f32x4 acc[4][4];
  #pragma unroll
  for (int i = 0; i < 4; i++)
    #pragma unroll
    for (int j = 0; j < 4; j++) acc[i][j] = (f32x4){0.f, 0.f, 0.f, 0.f};

  const int srow = tid >> 2;
  const int scol = (tid & 3) * 8;
  const bf16* gA0 = Ab + (size_t)(m0 + srow) * K + scol;
  const bf16* gB0 = Bbp + (size_t)(n0 + srow) * K + scol;
  bf16* lA = aT + wave * 512;   // wave-uniform LDS base (lane*16B auto-added)
  bf16* lB = bT + wave * 512;

  const int fm = lane & 15;
  const int kb = (lane >> 4) * 8;

  for (int kt = 0; kt < K; kt += 32) {
    gload_lds16(gA0 + kt, lA);
    gload_lds16(gA0 + (size_t)64 * K + kt, lA + 2048);
    gload_lds16(gB0 + kt, lB);
    gload_lds16(gB0 + (size_t)64 * K + kt, lB + 2048);
    __syncthreads();
    bf16x8 af[4], bf_[4];
    #pragma unroll
    for (int mf = 0; mf < 4; mf++)
      af[mf] = *(const bf16x8*)&aT[(wr * 64 + mf * 16 + fm) * 32 + kb];
    #pragma unroll
    for (int nf = 0; nf < 4; nf++)
      bf_[nf] = *(const bf16x8*)&bT[(wc * 64 + nf * 16 + fm) * 32 + kb];
    #pragma unroll
    for (int mf = 0; mf < 4; mf++)
      #pragma unroll
      for (int nf = 0; nf < 4; nf++)
        acc[mf][nf] = __builtin_amdgcn_mfma_f32_16x16x32_bf16(af[mf], bf_[nf], acc[mf][nf], 0, 0, 0);
    __syncthreads();
  }

  const int orow = (lane >> 4) * 4;
  const int ocol = lane & 15;
  if (STORE_BF16) {
    bf16* Cb = (bf16*)Cout + (size_t)b * Mrows * Ncols;
    #pragma unroll
    for (int mf = 0; mf < 4; mf++)
      #pragma unroll
      for (int nf = 0; nf < 4; nf++)
        #pragma unroll
        for (int r = 0; r < 4; r++) {
          int gm = m0 + wr * 64 + mf * 16 + orow + r;
          int gn = n0 + wc * 64 + nf * 16 + ocol;
          Cb[(size_t)gm * Ncols + gn] = __float2bfloat16(acc[mf][nf][r]);
        }
  } else {
    float* Cf = (float*)Cout + (size_t)b * Mrows * Ncols;
    #pragma unroll
    for (int mf = 0; mf < 4; mf++)
      #pragma unroll
      for (int nf = 0; nf < 4; nf++)
        #pragma unroll
        for (int r = 0; r < 4; r++) {
          int gm = m0 + wr * 64 + mf * 16 + orow + r;
          int gn = n0 + wc * 64 + nf * 16 + ocol;
          float v = acc[mf][nf][r];
          if (LEAKY) v = v >= 0.f ? v : 0.01f * v;
          Cf[(size_t)gm * Ncols + gn] = v;
        }
  }
}

// ---- wave-level inclusive scan over 64 lanes ------------------------------
__device__ __forceinline__ u32 wave_incl_scan(u32 v, int lane) {
  #pragma unroll
  for (int off = 1; off < 64; off <<= 1) {
    u32 t = __shfl_up(v, off, 64);
    if (lane >= off) v += t;
  }
  return v;
}

// ------------- per-row softmax + exact top-k mask (in place, bf16) --------
// Fully parallel: wave-shuffle reductions + block scans replace the serial
// tid==0 bin-select loops (which dominated the profile at 207us).
__global__ __launch_bounds__(256) void row_topk_softmax(bf16* __restrict__ S) {
  const int tid = threadIdx.x;
  const int lane = tid & 63;
  const int wave = tid >> 6;
  bf16* row = S + (size_t)blockIdx.x * Nn;
  uint4 raw = ((const uint4*)row)[tid];
  u32 w[4] = {raw.x, raw.y, raw.z, raw.w};
  u16 u[8]; float f[8]; u16 key[8];
  #pragma unroll
  for (int j = 0; j < 4; j++) { u[2 * j] = (u16)(w[j] & 0xFFFF); u[2 * j + 1] = (u16)(w[j] >> 16); }
  #pragma unroll
  for (int j = 0; j < 8; j++) {
    u32 bits = ((u32)u[j]) << 16;
    __builtin_memcpy(&f[j], &bits, 4);
    key[j] = (u[j] & 0x8000) ? (u16)(~u[j]) : (u16)(u[j] | 0x8000);
  }

  // ---- max reduction (wave shuffle + 4-way LDS combine) ----
  __shared__ float wred[4], wsum[4];
  float mx = f[0];
  #pragma unroll
  for (int j = 1; j < 8; j++) mx = fmaxf(mx, f[j]);
  #pragma unroll
  for (int off = 32; off > 0; off >>= 1) mx = fmaxf(mx, __shfl_xor(mx, off, 64));
  if (lane == 0) wred[wave] = mx;
  __syncthreads();
  mx = fmaxf(fmaxf(wred[0], wred[1]), fmaxf(wred[2], wred[3]));

  // ---- exp + sum reduction ----
  float e[8]; float se = 0.f;
  #pragma unroll
  for (int j = 0; j < 8; j++) { e[j] = __expf(f[j] - mx); se += e[j]; }
  #pragma unroll
  for (int off = 32; off > 0; off >>= 1) se += __shfl_xor(se, off, 64);
  if (lane == 0) wsum[wave] = se;
  __syncthreads();
  float inv_denom = 1.f / (wsum[0] + wsum[1] + wsum[2] + wsum[3]);

  // ---- radix pass 1: histogram of high byte of monotone key ----
  __shared__ u32 hist[256];
  __shared__ u32 woff[4];
  __shared__ u32 sres[2];
  hist[tid] = 0; __syncthreads();
  #pragma unroll
  for (int j = 0; j < 8; j++) atomicAdd(&hist[key[j] >> 8], 1u);
  __syncthreads();
  u32 cnt = hist[tid];
  u32 incl = wave_incl_scan(cnt, lane);
  if (lane == 63) woff[wave] = incl;
  __syncthreads();
  {
    u32 o = 0;
    #pragma unroll
    for (int ww = 0; ww < 4; ww++) if (ww < wave) o += woff[ww];
    incl += o;
  }
  if (incl > (u32)RANK && incl - cnt <= (u32)RANK) { sres[0] = (u32)tid; sres[1] = incl - cnt; }
  __syncthreads();
  u32 b1 = sres[0], below = sres[1];

  // ---- radix pass 2: histogram of low byte among keys in bucket b1 ----
  hist[tid] = 0; __syncthreads();
  #pragma unroll
  for (int j = 0; j < 8; j++) if ((u32)(key[j] >> 8) == b1) atomicAdd(&hist[key[j] & 0xFF], 1u);
  __syncthreads();
  cnt = hist[tid];
  incl = wave_incl_scan(cnt, lane);
  if (lane == 63) woff[wave] = incl;
  __syncthreads();
  {
    u32 o = 0;
    #pragma unroll
    for (int ww = 0; ww < 4; ww++) if (ww < wave) o += woff[ww];
    incl += o;
  }
  incl += below;
  if (incl > (u32)RANK && incl - cnt <= (u32)RANK) { sres[0] = (b1 << 8) | (u32)tid; sres[1] = incl; }
  __syncthreads();
  u16 tkey = (u16)sres[0];
  int keepEq = KKEEP - (Nn - (int)sres[1]);   // how many threshold-ties to keep (lowest index first)

  // ---- exclusive scan of per-thread tie counts (index-ordered) ----
  int eqc = 0;
  #pragma unroll
  for (int j = 0; j < 8; j++) eqc += (key[j] == tkey);
  __syncthreads();
  u32 eincl = wave_incl_scan((u32)eqc, lane);
  if (lane == 63) woff[wave] = eincl;
  __syncthreads();
  {
    u32 o = 0;
    #pragma unroll
    for (int ww = 0; ww < 4; ww++) if (ww < wave) o += woff[ww];
    eincl += o;
  }
  int eqseen = (int)eincl - eqc;

  u16 ob[8];
  #pragma unroll
  for (int j = 0; j < 8; j++) {
    float p = 0.f;
    if (key[j] > tkey) p = e[j] * inv_denom;
    else if (key[j] == tkey) { if (eqseen < keepEq) p = e[j] * inv_denom; eqseen++; }
    u32 pb; __builtin_memcpy(&pb, &p, 4);
    pb += 0x7FFF + ((pb >> 16) & 1);
    ob[j] = (u16)(pb >> 16);
  }
  uint4 outv;
  outv.x = (u32)ob[0] | ((u32)ob[1] << 16);
  outv.y = (u32)ob[2] | ((u32)ob[3] << 16);
  outv.z = (u32)ob[4] | ((u32)ob[5] << 16);
  outv.w = (u32)ob[6] | ((u32)ob[7] << 16);
  ((uint4*)row)[tid] = outv;
}

// ------------- BN stats ----------------------------------------------------
__global__ __launch_bounds__(256) void bn_partial(const float* __restrict__ y,
                                                  float* __restrict__ partial) {
  int bc = blockIdx.x;
  const float* p = y + (size_t)bc * Mm;
  int tid = threadIdx.x;
  float s = 0.f, ss = 0.f;
  for (int i = tid; i < Mm; i += 256) { float v = p[i]; s += v; ss += v * v; }
  __shared__ float r1[256], r2[256];
  r1[tid] = s; r2[tid] = ss; __syncthreads();
  for (int k = 128; k > 0; k >>= 1) { if (tid < k) { r1[tid] += r1[tid + k]; r2[tid] += r2[tid + k]; } __syncthreads(); }
  if (tid == 0) { partial[bc * 2] = r1[0]; partial[bc * 2 + 1] = r2[0]; }
}

__global__ __launch_bounds__(256) void bn_finalize(const float* __restrict__ partial,
                                                   const float* __restrict__ bnw,
                                                   const float* __restrict__ bnb,
                                                   float* __restrict__ scsh) {
  int c = threadIdx.x;
  float s = 0.f, ss = 0.f;
  for (int b = 0; b < Bb; b++) { s += partial[(b * Cch + c) * 2]; ss += partial[(b * Cch + c) * 2 + 1]; }
  float cnt = (float)(Bb * Mm);
  float mean = s / cnt;
  float var = ss / cnt - mean * mean;
  float scale = bnw[c] / sqrtf(var + 1e-5f);
  scsh[c * 2] = scale;
  scsh[c * 2 + 1] = bnb[c] - mean * scale;
}

// ------------- final: out = (y*scale+shift)*gamma + tg --------------------
__global__ __launch_bounds__(256) void final_kernel(float* io, const float* __restrict__ tg,
                                                    const float* __restrict__ scsh,
                                                    const float* __restrict__ gamma) {
  size_t n4 = (size_t)Bb * Cch * Mm / 4;
  float g = gamma[0];
  size_t stride = (size_t)gridDim.x * 256;
  for (size_t i = (size_t)blockIdx.x * 256 + threadIdx.x; i < n4; i += stride) {
    int c = (int)((i * 4 / Mm) % Cch);
    float4 v = ((const float4*)io)[i];
    float4 t = ((const float4*)tg)[i];
    float sc = scsh[c * 2], sh = scsh[c * 2 + 1];
    v.x = (v.x * sc + sh) * g + t.x;
    v.y = (v.y * sc + sh) * g + t.y;
    v.z = (v.z * sc + sh) * g + t.z;
    v.w = (v.w * sc + sh) * g + t.w;
    ((float4*)io)[i] = v;
  }
}

extern "C" void kernel_launch(void* const* d_in, const int* in_sizes, int n_in,
                              void* d_out, int out_size, void* d_ws, size_t ws_size,
                              hipStream_t stream) {
  (void)in_sizes; (void)n_in; (void)out_size; (void)ws_size;
  const float* x   = (const float*)d_in[0];
  const float* tg  = (const float*)d_in[1];
  const float* gamma = (const float*)d_in[2];
  const float* bnw = (const float*)d_in[3];
  const float* bnb = (const float*)d_in[4];
  float* out = (float*)d_out;

  char* ws = (char*)d_ws;
  float* inv_nx = (float*)ws; ws += (size_t)Bb * Nn * 4;
  float* inv_nt = (float*)ws; ws += (size_t)Bb * Mm * 4;
  bf16* xnT  = (bf16*)ws; ws += (size_t)Bb * Nn * Cch * 2;
  bf16* tgnT = (bf16*)ws; ws += (size_t)Bb * Mm * Cch * 2;
  bf16* xb   = (bf16*)ws; ws += (size_t)Bb * Cch * Nn * 2;
  bf16* S    = (bf16*)ws; ws += (size_t)Bb * Mm * Nn * 2;
  float* partial = (float*)ws; ws += (size_t)Bb * Cch * 2 * 4;
  float* scsh = (float*)ws; ws += (size_t)Cch * 2 * 4;

  norm_kernel<<<Bb * Nn / 256, 256, 0, stream>>>(x, inv_nx);
  norm_kernel<<<Bb * Mm / 256, 256, 0, stream>>>(tg, inv_nt);
  transpose_scale<<<dim3(Nn / 32, Cch / 32, Bb), dim3(32, 8), 0, stream>>>(x, inv_nx, xnT);
  transpose_scale<<<dim3(Mm / 32, Cch / 32, Bb), dim3(32, 8), 0, stream>>>(tg, inv_nt, tgnT);
  cvt_bf16<<<2048, 256, 0, stream>>>(x, xb, (size_t)Bb * Cch * Nn / 4);
  // S[b][m][n] = sum_c tgnT[b][m][c] * xnT[b][n][c]
  gemm_bt<1, 0><<<dim3(Mm / 128, Nn / 128, Bb), 256, 0, stream>>>(tgnT, xnT, S, Mm, Nn, Cch);
  row_topk_softmax<<<Bb * Mm, 256, 0, stream>>>(S);
  // out[b][c][m] = leaky( sum_n xb[b][c][n] * adj[b][m][n] )
  gemm_bt<0, 1><<<dim3(Cch / 128, Mm / 128, Bb), 256, 0, stream>>>(xb, S, out, Cch, Mm, Nn);
  bn_partial<<<Bb * Cch, 256, 0, stream>>>(out, partial);
  bn_finalize<<<1, 256, 0, stream>>>(partial, bnw, bnb, scsh);
  final_kernel<<<2048, 256, 0, stream>>>(out, tg, scsh, gamma);
}